// Round 10
// baseline (532.023 us; speedup 1.0000x reference)
//
#include <hip/hip_runtime.h>
#include <utility>

// 16-wire statevector sim, batch B. Chunk = fixed bits {15,14,13} (wires
// 0,1,2), 64KB LDS, 2 blocks/CU. Wire w <-> bit (15-w). Per layer l (r=l+1):
//  k_gen  (l=0): embed + all 16 Rots + CNOT cascade i=0..14 folded into a
//         closed-form product state at sigma0(u) = u ^ (u>>1). Write-only.
//  k_p1(l), l>=1: pure-register, group {15,14,13,0}: H3(l-1) wraps (tgt
//         w0,w1,w2), Rots{0,1,2,15}; l==1 also CNOT(w0->w2). f4 I/O.
//  k_mid(l), l=1..4: stage-in -> S1{12..9}:rots w3-6 -> S2{8..5}:w7-10 ->
//         S3{4..1}:w11-14 -> copy-out f4 where ALL in-chunk ring CNOTs are
//         one GF(2)-linear address map sigma_L (reverse-circuit XOR ladder,
//         evaluated once/thread; j-offsets are compile-time constants).
//  k_last (l=5): sweeps as k_mid, then readout from S3 regs with layer-5
//         CNOTs folded into Z-sign masks (Z-pullback derived).

#define NW    16
#define P1BLK 1024
#define P2BLK 512
#define CHUNK 8192
#define LDSN  (CHUNK + CHUNK / 16)

// ---------- static_for ----------
template<class F, int... Is>
__device__ __forceinline__ void static_for_impl(F&& f, std::integer_sequence<int, Is...>) {
    (f(std::integral_constant<int, Is>{}), ...);
}
template<int N, class F>
__device__ __forceinline__ void static_for(F&& f) {
    static_for_impl(f, std::make_integer_sequence<int, N>{});
}

__device__ __forceinline__ int pidx(int u) { return u + (u >> 4); }

// ---------- gate primitives ----------
__device__ __forceinline__ void c2x2(float2& a0, float2& a1,
                                     float2 m00, float2 m01,
                                     float2 m10, float2 m11) {
    float2 r0, r1;
    r0.x = m00.x*a0.x - m00.y*a0.y + m01.x*a1.x - m01.y*a1.y;
    r0.y = m00.x*a0.y + m00.y*a0.x + m01.x*a1.y + m01.y*a1.x;
    r1.x = m10.x*a0.x - m10.y*a0.y + m11.x*a1.x - m11.y*a1.y;
    r1.y = m10.x*a0.y + m10.y*a0.x + m11.x*a1.y + m11.y*a1.x;
    a0 = r0; a1 = r1;
}

__device__ __forceinline__ float2 cmul(float2 a, float2 b) {
    return make_float2(a.x*b.x - a.y*b.y, a.x*b.y + a.y*b.x);
}

template<int Q>
__device__ __forceinline__ void rot_regs(float2 a[16], float2 m00, float2 m01,
                                         float2 m10, float2 m11) {
#pragma unroll
    for (int j = 0; j < 16; ++j)
        if (!((j >> Q) & 1))
            c2x2(a[j], a[j | (1 << Q)], m00, m01, m10, m11);
}

template<int QC, int QT>
__device__ __forceinline__ void cnot_inreg(float2 a[16]) {
#pragma unroll
    for (int j = 0; j < 16; ++j)
        if (((j >> QC) & 1) && !((j >> QT) & 1)) {
            float2 t = a[j]; a[j] = a[j | (1 << QT)]; a[j | (1 << QT)] = t;
        }
}

template<int QT>
__device__ __forceinline__ void cnot_ctrlout(float2 a[16], int ctrl) {
#pragma unroll
    for (int j = 0; j < 16; ++j)
        if (!((j >> QT) & 1)) {
            int j2 = j | (1 << QT);
            float2 x = a[j], y = a[j2];
            a[j].x  = ctrl ? y.x : x.x;  a[j].y  = ctrl ? y.y : x.y;
            a[j2].x = ctrl ? x.x : y.x;  a[j2].y = ctrl ? x.y : y.y;
        }
}

// Rot(phi,theta,omega) = RZ(omega) RY(theta) RZ(phi)
__device__ __forceinline__ void rot_mat(const float* ww, float2 m[4]) {
    float phi = ww[0], th = ww[1], om = ww[2];
    float ct, st;   sincosf(0.5f * th, &st, &ct);
    float cap, sap; sincosf(0.5f * (phi + om), &sap, &cap);
    float cam, sam; sincosf(0.5f * (phi - om), &sam, &cam);
    m[0] = make_float2( cap * ct, -sap * ct);
    m[1] = make_float2(-cam * st, -sam * st);
    m[2] = make_float2( cam * st, -sam * st);
    m[3] = make_float2( cap * ct,  sap * ct);
}

// ---------- sigma_L: composed in-chunk CNOT permutation (linear over GF2) ----
// Reverse-circuit-order XOR ladder; chunk-bit ctrls (>=13) read raw bits.
#define SSTEP(cb, tb) s ^= ((s >> (cb)) & 1) << (tb);
template<int L>
constexpr int sigma_cx(int s) {
    if constexpr (L == 1) {        // i=13..1 (i=0 handled in k_p1<1>)
        SSTEP(2,0) SSTEP(3,1) SSTEP(4,2) SSTEP(5,3) SSTEP(6,4) SSTEP(7,5)
        SSTEP(8,6) SSTEP(9,7) SSTEP(10,8) SSTEP(11,9) SSTEP(12,10)
        SSTEP(13,11) SSTEP(14,12)
    } else if constexpr (L == 2) { // i=12..0
        SSTEP(3,0) SSTEP(4,1) SSTEP(5,2) SSTEP(6,3) SSTEP(7,4) SSTEP(8,5)
        SSTEP(9,6) SSTEP(10,7) SSTEP(11,8) SSTEP(12,9) SSTEP(13,10)
        SSTEP(14,11) SSTEP(15,12)
    } else if constexpr (L == 3) { // wrap i=15 then i=11..0
        SSTEP(0,12)
        SSTEP(4,0) SSTEP(5,1) SSTEP(6,2) SSTEP(7,3) SSTEP(8,4) SSTEP(9,5)
        SSTEP(10,6) SSTEP(11,7) SSTEP(12,8) SSTEP(13,9) SSTEP(14,10)
        SSTEP(15,11)
    } else if constexpr (L == 4) { // wraps i=15,14 then i=10..0
        SSTEP(0,11) SSTEP(1,12)
        SSTEP(5,0) SSTEP(6,1) SSTEP(7,2) SSTEP(8,3) SSTEP(9,4) SSTEP(10,5)
        SSTEP(11,6) SSTEP(12,7) SSTEP(13,8) SSTEP(14,9) SSTEP(15,10)
    }
    return s;
}
#undef SSTEP

// ---------- k_gen: layer 0 closed-form generation (write-only) ----------
__global__ __launch_bounds__(P2BLK)
void k_gen(const float* __restrict__ x, const float* __restrict__ w,
           float2* __restrict__ psi) {
    __shared__ float2 gm[NW][4];
    __shared__ float  ecs[NW], ess[NW];
    const int b = blockIdx.x >> 3, c = blockIdx.x & 7;
    const int tid = threadIdx.x;
    float2* g = psi + ((size_t)b << 16) + ((size_t)c << 13);

    if (tid < NW) {
        rot_mat(w + tid * 3, gm[tid]);
        float s_, c_; sincosf(0.5f * x[b * NW + tid], &s_, &c_);
        ecs[tid] = c_; ess[tid] = s_;
    }
    __syncthreads();

    // per-wire single-qubit state v_w[bit] = Rot_w RY(x_w)|0>
    auto fsel = [&](int wq, int bit) {
        float2 glo = gm[wq][2*bit], ghi = gm[wq][2*bit+1];
        return make_float2(glo.x * ecs[wq] + ghi.x * ess[wq],
                           glo.y * ecs[wq] + ghi.y * ess[wq]);
    };

    const int U0 = (c << 13) | (tid << 4);
    const int S0 = U0 ^ (U0 >> 1);          // sigma0: cascade CNOTs i=0..14

    float2 common = fsel(0, (S0 >> 15) & 1);
#pragma unroll
    for (int wq = 1; wq < 12; ++wq)
        common = cmul(common, fsel(wq, (S0 >> (15 - wq)) & 1));

#pragma unroll
    for (int j = 0; j < 16; j += 2) {
        float2 amp2[2];
#pragma unroll
        for (int k = 0; k < 2; ++k) {
            int U = U0 | (j + k);
            int S = U ^ (U >> 1);
            float2 t = cmul(common, fsel(12, (S >> 3) & 1));
            t = cmul(t, fsel(13, (S >> 2) & 1));
            t = cmul(t, fsel(14, (S >> 1) & 1));
            t = cmul(t, fsel(15, S & 1));
            amp2[k] = t;
        }
        reinterpret_cast<float4*>(g)[(tid << 3) | (j >> 1)] =
            make_float4(amp2[0].x, amp2[0].y, amp2[1].x, amp2[1].y);
    }
}

// ---------- k_p1 (l>=1): pure register, group {15,14,13,0}, f4 I/O ----------
template<int LL>
__global__ __launch_bounds__(P1BLK)
void k_p1(const float* __restrict__ w, float2* __restrict__ psi) {
    const int b = blockIdx.x >> 2;
    const int T = ((blockIdx.x & 3) << 10) | (int)threadIdx.x;   // 12-bit
    float2* g = psi + ((size_t)b << 16);
    const int sb = T << 1;                                       // bits 12..1

    float2 m0[4], m1[4], m2[4], m15[4];
    rot_mat(w + (LL * NW + 0) * 3, m0);
    rot_mat(w + (LL * NW + 1) * 3, m1);
    rot_mat(w + (LL * NW + 2) * 3, m2);
    rot_mat(w + (LL * NW + 15) * 3, m15);

    // reg j: b0<->bit0(w15), b1<->bit13(w2), b2<->bit14(w1), b3<->bit15(w0)
    float2 a[16];
#pragma unroll
    for (int jh = 0; jh < 8; ++jh) {
        int s = sb | ((jh & 1) << 13) | (((jh >> 1) & 1) << 14) | (((jh >> 2) & 1) << 15);
        float4 f = *reinterpret_cast<const float4*>(g + s);
        a[(jh << 1)]     = make_float2(f.x, f.y);
        a[(jh << 1) | 1] = make_float2(f.z, f.w);
    }

    // H3(LL-1): layer-(LL-1) wraps targeting w0,w1,w2
    if constexpr (LL == 1) {
        cnot_inreg<0, 3>(a);                      // CNOT(w15->w0)
    } else if constexpr (LL == 2) {
        cnot_ctrlout<3>(a, (sb >> 1) & 1);        // CNOT(w14->w0)
        cnot_inreg<0, 2>(a);                      // CNOT(w15->w1)
    } else if constexpr (LL == 3) {
        cnot_ctrlout<3>(a, (sb >> 2) & 1);
        cnot_ctrlout<2>(a, (sb >> 1) & 1);
        cnot_inreg<0, 1>(a);
    } else if constexpr (LL == 4) {
        cnot_ctrlout<3>(a, (sb >> 3) & 1);
        cnot_ctrlout<2>(a, (sb >> 2) & 1);
        cnot_ctrlout<1>(a, (sb >> 1) & 1);
    } else {
        cnot_ctrlout<3>(a, (sb >> 4) & 1);
        cnot_ctrlout<2>(a, (sb >> 3) & 1);
        cnot_ctrlout<1>(a, (sb >> 2) & 1);
    }

    rot_regs<3>(a, m0[0],  m0[1],  m0[2],  m0[3]);    // Rot w0
    rot_regs<2>(a, m1[0],  m1[1],  m1[2],  m1[3]);    // Rot w1
    rot_regs<1>(a, m2[0],  m2[1],  m2[2],  m2[3]);    // Rot w2
    rot_regs<0>(a, m15[0], m15[1], m15[2], m15[3]);   // Rot w15
    if constexpr (LL == 1) cnot_inreg<3, 1>(a);       // layer-1 i=0: CNOT(w0->w2)

#pragma unroll
    for (int jh = 0; jh < 8; ++jh) {
        int s = sb | ((jh & 1) << 13) | (((jh >> 1) & 1) << 14) | (((jh >> 2) & 1) << 15);
        float2 lo = a[(jh << 1)], hi = a[(jh << 1) | 1];
        *reinterpret_cast<float4*>(g + s) = make_float4(lo.x, lo.y, hi.x, hi.y);
    }
}

// ---------- shared sweep body: S1,S2,S3 pure-rot register sweeps ----------
template<int L>
__device__ __forceinline__ void sweeps123(float2 (*gm)[4], float2* lds,
                                          float2 a[16], int tid,
                                          const float2* __restrict__ g) {
    // S1: bits 12..9 = wires 3..6 (stage-in already in a[])
    rot_regs<3>(a, gm[3][0], gm[3][1], gm[3][2], gm[3][3]);
    rot_regs<2>(a, gm[4][0], gm[4][1], gm[4][2], gm[4][3]);
    rot_regs<1>(a, gm[5][0], gm[5][1], gm[5][2], gm[5][3]);
    rot_regs<0>(a, gm[6][0], gm[6][1], gm[6][2], gm[6][3]);
#pragma unroll
    for (int j = 0; j < 16; ++j) lds[pidx(tid | (j << 9))] = a[j];
    __syncthreads();
    {   // S2: bits 8..5 = wires 7..10
        const int ub = (tid & 31) | ((tid >> 5) << 9);
#pragma unroll
        for (int j = 0; j < 16; ++j) a[j] = lds[pidx(ub | (j << 5))];
        rot_regs<3>(a, gm[7][0],  gm[7][1],  gm[7][2],  gm[7][3]);
        rot_regs<2>(a, gm[8][0],  gm[8][1],  gm[8][2],  gm[8][3]);
        rot_regs<1>(a, gm[9][0],  gm[9][1],  gm[9][2],  gm[9][3]);
        rot_regs<0>(a, gm[10][0], gm[10][1], gm[10][2], gm[10][3]);
#pragma unroll
        for (int j = 0; j < 16; ++j) lds[pidx(ub | (j << 5))] = a[j];
    }
    __syncthreads();
    {   // S3: bits 4..1 = wires 11..14
        const int ub = (tid & 1) | ((tid >> 1) << 5);
#pragma unroll
        for (int j = 0; j < 16; ++j) a[j] = lds[pidx(ub | (j << 1))];
        rot_regs<3>(a, gm[11][0], gm[11][1], gm[11][2], gm[11][3]);
        rot_regs<2>(a, gm[12][0], gm[12][1], gm[12][2], gm[12][3]);
        rot_regs<1>(a, gm[13][0], gm[13][1], gm[13][2], gm[13][3]);
        rot_regs<0>(a, gm[14][0], gm[14][1], gm[14][2], gm[14][3]);
    }
}

// ---------- k_mid (l=1..4): rots + sigma-folded copy-out ----------
template<int L>
__global__ __launch_bounds__(P2BLK, 4)
void k_mid(const float* __restrict__ w, float2* __restrict__ psi) {
    __shared__ float2 lds[LDSN];
    __shared__ float2 gm[NW][4];
    const int b = blockIdx.x >> 3, c = blockIdx.x & 7;
    const int tid = threadIdx.x;
    float2* g = psi + ((size_t)b << 16) + ((size_t)c << 13);

    if (tid < NW) rot_mat(w + (L * NW + tid) * 3, gm[tid]);
    float2 a[16];
#pragma unroll
    for (int j = 0; j < 16; ++j) a[j] = g[tid | (j << 9)];   // wave-contiguous
    __syncthreads();

    sweeps123<L>(gm, lds, a, tid, g);
    {   // S3 regs -> LDS, then sigma-folded f4 copy-out
        const int ub = (tid & 1) | ((tid >> 1) << 5);
#pragma unroll
        for (int j = 0; j < 16; ++j) lds[pidx(ub | (j << 1))] = a[j];
    }
    __syncthreads();

    const int sbase = sigma_cx<L>((c << 13) | (tid << 1));
    constexpr int D0 = sigma_cx<L>(1);
    static_for<CHUNK / 2 / P2BLK>([&](auto ITC) {
        constexpr int IT  = decltype(ITC)::value;
        constexpr int KIT = sigma_cx<L>(IT << 10);     // linearity
        int ae = sbase ^ KIT;
        float2 lo = lds[pidx(ae & 0x1FFF)];
        float2 hi = lds[pidx((ae ^ D0) & 0x1FFF)];
        reinterpret_cast<float4*>(g)[tid + IT * P2BLK] =
            make_float4(lo.x, lo.y, hi.x, hi.y);
    });
}

// ---------- k_last (l=5): rots + readout with CNOTs folded into Z signs ----
__global__ __launch_bounds__(P2BLK, 4)
void k_last(const float* __restrict__ w, float* __restrict__ out,
            float2* __restrict__ psi) {
    __shared__ float2 lds[LDSN];
    __shared__ float2 gm[NW][4];
    __shared__ float  accs[NW];
    const int b = blockIdx.x >> 3, c = blockIdx.x & 7;
    const int tid = threadIdx.x;
    float2* g = psi + ((size_t)b << 16) + ((size_t)c << 13);

    if (tid < NW) { rot_mat(w + (5 * NW + tid) * 3, gm[tid]); accs[tid] = 0.f; }
    float2 a[16];
#pragma unroll
    for (int j = 0; j < 16; ++j) a[j] = g[tid | (j << 9)];
    __syncthreads();

    sweeps123<5>(gm, lds, a, tid, g);

    // readout from S3 regs: j bits 3..0 <-> s bits 4..1; s0 = tid&1;
    // s12..5 = tid>>1; c = s15..13. Sign masks = Z pullback through all
    // 16 layer-5 CNOTs (r=6), derived offline.
    float psum = 0.f, sb3 = 0.f, sb2 = 0.f, sb1 = 0.f, sb0 = 0.f;
#pragma unroll
    for (int j = 0; j < 16; ++j) {
        float2 v = a[j];
        float p = v.x * v.x + v.y * v.y;
        psum += p;
        sb3 += (j & 8) ? -p : p;
        sb2 += (j & 4) ? -p : p;
        sb1 += (j & 2) ? -p : p;
        sb0 += (j & 1) ? -p : p;
    }
    const int q  = tid & 1;
    const int t1 = (tid >> 1) & 1, t2 = (tid >> 2) & 1, t3 = (tid >> 3) & 1;
    const int t4 = (tid >> 4) & 1, t5 = (tid >> 5) & 1, t6 = (tid >> 6) & 1;
    const int t7 = (tid >> 7) & 1, t8 = (tid >> 8) & 1;
    const int c13 = c & 1, c14 = (c >> 1) & 1, c15 = (c >> 2) & 1;

    float z[NW];
    z[0]  = ((c15 ^ t7 ^ t1) & 1)       ? -psum : psum;
    z[1]  = ((c14 ^ t6) & 1)            ? -sb3  : sb3;
    z[2]  = ((c15 ^ c13 ^ t5) & 1)      ? -sb2  : sb2;
    z[3]  = ((c14 ^ t8 ^ t4) & 1)       ? -sb1  : sb1;
    z[4]  = ((c13 ^ t7 ^ t3) & 1)       ? -sb0  : sb0;
    z[5]  = ((t8 ^ t6 ^ t2 ^ q) & 1)    ? -psum : psum;
    z[6]  = ((c15 ^ t5) & 1)            ? -psum : psum;
    z[7]  = ((c14 ^ t4) & 1)            ? -psum : psum;
    z[8]  = ((c13 ^ t3) & 1)            ? -psum : psum;
    z[9]  = ((t8 ^ t2) & 1)             ? -psum : psum;
    z[10] = ((t7 ^ t1) & 1)             ? -psum : psum;
    z[11] = (t6 & 1)                    ? -sb3  : sb3;
    z[12] = ((c15 ^ t5) & 1)            ? -sb2  : sb2;
    z[13] = ((c14 ^ t4) & 1)            ? -sb1  : sb1;
    z[14] = ((c13 ^ t3) & 1)            ? -sb0  : sb0;
    z[15] = ((t8 ^ t2 ^ q) & 1)         ? -psum : psum;

#pragma unroll
    for (int i = 0; i < NW; ++i) {
        float v = z[i];
#pragma unroll
        for (int off = 32; off > 0; off >>= 1) v += __shfl_down(v, off, 64);
        if ((tid & 63) == 0) atomicAdd(&accs[i], v);
    }
    __syncthreads();
    if (tid < NW) atomicAdd(&out[b * NW + tid], accs[tid]);
}

extern "C" void kernel_launch(void* const* d_in, const int* in_sizes, int n_in,
                              void* d_out, int out_size, void* d_ws, size_t ws_size,
                              hipStream_t stream) {
    const float* x = (const float*)d_in[0];   // (B, 16) float32
    const float* w = (const float*)d_in[1];   // (6, 16, 3) float32
    float* out = (float*)d_out;               // (B, 16) float32
    float2* psi = (float2*)d_ws;              // B * 65536 * 8 B

    const int batch = in_sizes[0] / NW;
    const int g1 = batch * 4;                 // P1 grid
    const int g2 = batch * 8;                 // P2 grid

    hipMemsetAsync(d_out, 0, (size_t)out_size * sizeof(float), stream);

    k_gen<<<g2, P2BLK, 0, stream>>>(x, w, psi);
    k_p1<1><<<g1, P1BLK, 0, stream>>>(w, psi);
    k_mid<1><<<g2, P2BLK, 0, stream>>>(w, psi);
    k_p1<2><<<g1, P1BLK, 0, stream>>>(w, psi);
    k_mid<2><<<g2, P2BLK, 0, stream>>>(w, psi);
    k_p1<3><<<g1, P1BLK, 0, stream>>>(w, psi);
    k_mid<3><<<g2, P2BLK, 0, stream>>>(w, psi);
    k_p1<4><<<g1, P1BLK, 0, stream>>>(w, psi);
    k_mid<4><<<g2, P2BLK, 0, stream>>>(w, psi);
    k_p1<5><<<g1, P1BLK, 0, stream>>>(w, psi);
    k_last<<<g2, P2BLK, 0, stream>>>(w, out, psi);
}